// Round 4
// baseline (30.738 us; speedup 1.0000x reference)
//
#include <hip/hip_runtime.h>
#include <math.h>

constexpr int NT   = 256;   // threads per block
constexpr int DIMV = 256;   // volume D=H=W
constexpr int RS   = 8;     // staged region side (voxels)
constexpr int RROW = 9;     // padded row stride in floats
constexpr int RSLICE = RS * RROW;  // 72 floats per z-slice

__device__ __forceinline__ float rflf(float x) {
    // block-uniform value -> SGPR (exact: all lanes identical by construction)
    return __uint_as_float(__builtin_amdgcn_readfirstlane(__float_as_uint(x)));
}
__device__ __forceinline__ float fexp2(float x) {
#if __has_builtin(__builtin_amdgcn_exp2f)
    return __builtin_amdgcn_exp2f(x);
#else
    return __expf(x * 0.6931471805599453f);
#endif
}

__global__ __launch_bounds__(NT, 6) void psf_sample_kernel(
    const float* __restrict__ vol,         // [256^3]
    const float* __restrict__ sampleGrid,  // [B,3]
    const float* __restrict__ ax,          // [B,6]  (v[3], t[3])
    const float* __restrict__ bound,       // [B,2,3]
    const float* __restrict__ invcov,      // [B,3,3] (symmetric)
    const float* __restrict__ xyz,         // [B,n,3]
    float* __restrict__ out,               // [B]
    int n)
{
    const int b   = blockIdx.x;
    const int tid = threadIdx.x;

    __shared__ float s_vol[RS * RSLICE];      // 576 floats = 2304 B
    __shared__ float s_red[2 * (NT / 64)];

    // ---- per-block params (uniform; computed redundantly, then SGPR-ified) ----
    const float v0 = ax[b*6+0], v1 = ax[b*6+1], v2 = ax[b*6+2];
    const float t0 = ax[b*6+3], t1 = ax[b*6+4], t2 = ax[b*6+5];
    const float theta = sqrtf(v0*v0 + v1*v1 + v2*v2 + 1e-12f);
    const float inv = 1.0f / theta;
    const float kx = v0*inv, ky = v1*inv, kz = v2*inv;
    const float sn = sinf(theta);
    const float cn = 1.0f - cosf(theta);
    const float R00 = 1.0f - cn*(ky*ky + kz*kz);
    const float R01 = -sn*kz + cn*kx*ky;
    const float R02 =  sn*ky + cn*kx*kz;
    const float R10 =  sn*kz + cn*kx*ky;
    const float R11 = 1.0f - cn*(kx*kx + kz*kz);
    const float R12 = -sn*kx + cn*ky*kz;
    const float R20 = -sn*ky + cn*kx*kz;
    const float R21 =  sn*kx + cn*ky*kz;
    const float R22 = 1.0f - cn*(kx*kx + ky*ky);
    const float g0 = sampleGrid[b*3+0] + t0;
    const float g1 = sampleGrid[b*3+1] + t1;
    const float g2 = sampleGrid[b*3+2] + t2;
    const float ms0 = R00*g0 + R01*g1 + R02*g2;
    const float ms1 = R10*g0 + R11*g1 + R12*g2;
    const float ms2 = R20*g0 + R21*g1 + R22*g2;
    const float h0 = (bound[b*6+3] - bound[b*6+0]) * 0.5f;
    const float h1 = (bound[b*6+4] - bound[b*6+1]) * 0.5f;
    const float h2 = (bound[b*6+5] - bound[b*6+2]) * 0.5f;
    const float M00 = invcov[b*9+0], M01 = invcov[b*9+1], M02 = invcov[b*9+2];
    const float M11 = invcov[b*9+4], M12 = invcov[b*9+5], M22 = invcov[b*9+8];

    const float LOG2E = 1.4426950408889634f;
    // w = exp2( Bxx sx^2 + Byy sy^2 + Bzz sz^2 + Bxy sx sy + Bxz sx sz + Byz sy sz )
    const float Bxx = rflf(-0.5f * M00 * h0 * h0 * LOG2E);
    const float Byy = rflf(-0.5f * M11 * h1 * h1 * LOG2E);
    const float Bzz = rflf(-0.5f * M22 * h2 * h2 * LOG2E);
    const float Bxy = rflf(-M01 * h0 * h1 * LOG2E);
    const float Bxz = rflf(-M02 * h0 * h2 * LOG2E);
    const float Byz = rflf(-M12 * h1 * h2 * LOG2E);

    // voxel index: i = p*(256/255) - 0.5  (algebraic reduction of ref round-trip)
    const float kk = 256.0f / 255.0f;
    const float cix = rflf(fmaf(ms0, kk, -0.5f));
    const float ciy = rflf(fmaf(ms1, kk, -0.5f));
    const float ciz = rflf(fmaf(ms2, kk, -0.5f));
    const float hx = rflf(h0 * kk);
    const float hy = rflf(h1 * kk);
    const float hz = rflf(h2 * kk);

    const int bx = __builtin_amdgcn_readfirstlane((int)floorf(cix - hx - 1e-3f));
    const int by = __builtin_amdgcn_readfirstlane((int)floorf(ciy - hy - 1e-3f));
    const int bz = __builtin_amdgcn_readfirstlane((int)floorf(ciz - hz - 1e-3f));
    // element-index offset constant (exact small integer)
    const float addrC = rflf((float)(bz * RSLICE + by * RROW + bx));
    // fast path valid iff local span fits RS-1: needs 2h*kk + 1.001 < 7 (h <= 2.51 here)
    const bool fast = (hx <= 2.9f) && (hy <= 2.9f) && (hz <= 2.9f);

    if (fast) {
        #pragma unroll
        for (int pass = 0; pass < (RS*RS*RS)/NT; ++pass) {
            const int idx = pass * NT + tid;
            const int lx = idx & 7, ly = (idx >> 3) & 7, lz = idx >> 6;
            const int gx = bx + lx, gy = by + ly, gz = bz + lz;
            float v = 0.0f;
            if ((unsigned)gx < (unsigned)DIMV && (unsigned)gy < (unsigned)DIMV &&
                (unsigned)gz < (unsigned)DIMV)
                v = vol[((size_t)gz * DIMV + gy) * DIMV + gx];
            s_vol[(lz * RS + ly) * RROW + lx] = v;
        }
    }
    __syncthreads();

    float sum_wx = 0.0f, sum_w = 0.0f;

    auto doSample = [&](float rx, float ry, float rz) {
        // s = 2*sigmoid(r)-1 = (1-e)/(1+e), e = exp2(-r*log2e)
        const float ex = fexp2(rx * -LOG2E);
        const float ey = fexp2(ry * -LOG2E);
        const float ez = fexp2(rz * -LOG2E);
        const float sx = (1.0f - ex) * __builtin_amdgcn_rcpf(1.0f + ex);
        const float sy = (1.0f - ey) * __builtin_amdgcn_rcpf(1.0f + ey);
        const float sz = (1.0f - ez) * __builtin_amdgcn_rcpf(1.0f + ez);

        const float ixf = fmaf(sx, hx, cix);
        const float iyf = fmaf(sy, hy, ciy);
        const float izf = fmaf(sz, hz, ciz);
        const float x0f = floorf(ixf), y0f = floorf(iyf), z0f = floorf(izf);
        const float fx = ixf - x0f, fy = iyf - y0f, fz = izf - z0f;

        float val;
        if (fast) {
            // float-domain element index (exact: all terms small integers)
            const float ef = fmaf(z0f, (float)RSLICE,
                             fmaf(y0f, (float)RROW, x0f - addrC));
            const int e = (int)ef;
            const float* p = &s_vol[e];
            const float v000 = p[0],              v001 = p[1];
            const float v010 = p[RROW],           v011 = p[RROW + 1];
            const float v100 = p[RSLICE],         v101 = p[RSLICE + 1];
            const float v110 = p[RSLICE + RROW],  v111 = p[RSLICE + RROW + 1];
            const float a00 = fmaf(fx, v001 - v000, v000);
            const float a01 = fmaf(fx, v011 - v010, v010);
            const float a10 = fmaf(fx, v101 - v100, v100);
            const float a11 = fmaf(fx, v111 - v110, v110);
            const float a0  = fmaf(fy, a01 - a00, a00);
            const float a1  = fmaf(fy, a11 - a10, a10);
            val = fmaf(fz, a1 - a0, a0);
        } else {
            const int x0 = (int)x0f, y0 = (int)y0f, z0 = (int)z0f;
            const int x1 = x0 + 1, y1 = y0 + 1, z1 = z0 + 1;
            const bool vx0 = (unsigned)x0 < (unsigned)DIMV;
            const bool vx1 = (unsigned)x1 < (unsigned)DIMV;
            const bool vy0 = (unsigned)y0 < (unsigned)DIMV;
            const bool vy1 = (unsigned)y1 < (unsigned)DIMV;
            const bool vz0 = (unsigned)z0 < (unsigned)DIMV;
            const bool vz1 = (unsigned)z1 < (unsigned)DIMV;
            const int cx0 = min(max(x0,0),DIMV-1), cx1 = min(max(x1,0),DIMV-1);
            const int cy0 = min(max(y0,0),DIMV-1), cy1 = min(max(y1,0),DIMV-1);
            const int cz0 = min(max(z0,0),DIMV-1), cz1 = min(max(z1,0),DIMV-1);
            const float wx0 = 1.0f-fx, wx1 = fx, wy0 = 1.0f-fy, wy1 = fy;
            const float wz0 = 1.0f-fz, wz1 = fz;
            const int r00 = (cz0*DIMV + cy0)*DIMV, r01 = (cz0*DIMV + cy1)*DIMV;
            const int r10 = (cz1*DIMV + cy0)*DIMV, r11 = (cz1*DIMV + cy1)*DIMV;
            val  = (vz0&&vy0&&vx0) ? vol[r00+cx0]*(wz0*wy0*wx0) : 0.0f;
            val += (vz0&&vy0&&vx1) ? vol[r00+cx1]*(wz0*wy0*wx1) : 0.0f;
            val += (vz0&&vy1&&vx0) ? vol[r01+cx0]*(wz0*wy1*wx0) : 0.0f;
            val += (vz0&&vy1&&vx1) ? vol[r01+cx1]*(wz0*wy1*wx1) : 0.0f;
            val += (vz1&&vy0&&vx0) ? vol[r10+cx0]*(wz1*wy0*wx0) : 0.0f;
            val += (vz1&&vy0&&vx1) ? vol[r10+cx1]*(wz1*wy0*wx1) : 0.0f;
            val += (vz1&&vy1&&vx0) ? vol[r11+cx0]*(wz1*wy1*wx0) : 0.0f;
            val += (vz1&&vy1&&vx1) ? vol[r11+cx1]*(wz1*wy1*wx1) : 0.0f;
        }

        const float f = fmaf(Bxx, sx*sx,
                        fmaf(Byy, sy*sy,
                        fmaf(Bzz, sz*sz,
                        fmaf(Bxy, sx*sy,
                        fmaf(Bxz, sx*sz, Byz * (sy*sz))))));
        const float w = fexp2(f);
        sum_w  += w;
        sum_wx = fmaf(w, val, sum_wx);
    };

    // 4 samples per group via 3 coalesced float4 loads; 2 groups in flight
    const int ng = n >> 2;
    const float4* __restrict__ xb4 =
        reinterpret_cast<const float4*>(xyz + (size_t)b * n * 3);
    for (int g = tid; g < ng; g += 2*NT) {
        const float4 a0 = xb4[g*3 + 0];
        const float4 a1 = xb4[g*3 + 1];
        const float4 a2 = xb4[g*3 + 2];
        const int g2 = g + NT;
        const bool has2 = g2 < ng;
        float4 c0, c1, c2;
        if (has2) { c0 = xb4[g2*3 + 0]; c1 = xb4[g2*3 + 1]; c2 = xb4[g2*3 + 2]; }
        doSample(a0.x, a0.y, a0.z);
        doSample(a0.w, a1.x, a1.y);
        doSample(a1.z, a1.w, a2.x);
        doSample(a2.y, a2.z, a2.w);
        if (has2) {
            doSample(c0.x, c0.y, c0.z);
            doSample(c0.w, c1.x, c1.y);
            doSample(c1.z, c1.w, c2.x);
            doSample(c2.y, c2.z, c2.w);
        }
    }
    // generic tail (unused when n % 4 == 0)
    const float* __restrict__ xb = xyz + (size_t)b * n * 3;
    for (int i = (ng << 2) + tid; i < n; i += NT)
        doSample(xb[i*3+0], xb[i*3+1], xb[i*3+2]);

    // wave64 reduction
    #pragma unroll
    for (int off = 32; off > 0; off >>= 1) {
        sum_wx += __shfl_down(sum_wx, off);
        sum_w  += __shfl_down(sum_w,  off);
    }
    const int wave = tid >> 6;
    const int lane = tid & 63;
    if (lane == 0) { s_red[wave*2] = sum_wx; s_red[wave*2+1] = sum_w; }
    __syncthreads();
    if (tid == 0) {
        float twx = 0.0f, tw = 0.0f;
        #pragma unroll
        for (int wv = 0; wv < NT/64; ++wv) { twx += s_red[wv*2]; tw += s_red[wv*2+1]; }
        out[b] = twx / tw;
    }
}

extern "C" void kernel_launch(void* const* d_in, const int* in_sizes, int n_in,
                              void* d_out, int out_size, void* d_ws, size_t ws_size,
                              hipStream_t stream) {
    const float* vol        = (const float*)d_in[0];
    const float* sampleGrid = (const float*)d_in[1];
    const float* ax         = (const float*)d_in[2];
    const float* bound      = (const float*)d_in[3];
    const float* invcov     = (const float*)d_in[4];
    // d_in[5] = psf_sigma (unused by reference)
    const float* xyz        = (const float*)d_in[6];
    float* out              = (float*)d_out;

    const int B = in_sizes[1] / 3;
    const int n = in_sizes[6] / (B * 3);

    psf_sample_kernel<<<B, NT, 0, stream>>>(vol, sampleGrid, ax, bound, invcov,
                                            xyz, out, n);
}